// Round 4
// baseline (190.186 us; speedup 1.0000x reference)
//
#include <hip/hip_runtime.h>
#include <math.h>

#define NSTATE 64
#define LEN    4096
#define NH     256
#define NB     16

typedef float f2 __attribute__((ext_vector_type(2)));

// K in base-8 digit-reversed order (fftconv consumption order).
__device__ f2 g_ksym[NH * LEN];
// per-(h,n) Cauchy params: A={lam_r,lam_i,|P|^2,pad} B={v0r,v0i,v1r,v1i} C={v2r,v2i}
// Global (not LDS): read via wave-uniform s_load -> scalar cache, zero DS-pipe cost.
__device__ float4 g_pA[NH * NSTATE];
__device__ float4 g_pB[NH * NSTATE];
__device__ float2 g_pC[NH * NSTATE];

__device__ __forceinline__ int rev8_12(int p) {
  return ((p & 7) << 9) | (((p >> 3) & 7) << 6) | (((p >> 6) & 7) << 3) | (p >> 9);
}

__device__ __forceinline__ f2 mkf2(float a, float b){ f2 r; r.x = a; r.y = b; return r; }

// ---------------- packed-f32 complex primitives (VOP3P) ----------------
__device__ __forceinline__ f2 cmul_pk(f2 a, f2 b) {
  f2 t, r;
  asm("v_pk_mul_f32 %0, %1, %2 op_sel:[0,0] op_sel_hi:[0,1]"
      : "=v"(t) : "v"(a), "v"(b));
  asm("v_pk_fma_f32 %0, %1, %2, %3 op_sel:[1,1,0] op_sel_hi:[1,0,1] neg_lo:[0,1,0]"
      : "=v"(r) : "v"(a), "v"(b), "v"(t));
  return r;
}
__device__ __forceinline__ f2 cmulc_pk(f2 a, f2 b) {
  f2 t, r;
  asm("v_pk_mul_f32 %0, %1, %2 op_sel:[0,0] op_sel_hi:[0,1] neg_hi:[0,1]"
      : "=v"(t) : "v"(a), "v"(b));
  asm("v_pk_fma_f32 %0, %1, %2, %3 op_sel:[1,1,0] op_sel_hi:[1,0,1]"
      : "=v"(r) : "v"(a), "v"(b), "v"(t));
  return r;
}
__device__ __forceinline__ void cmac_pk(f2& acc, f2 v, f2 e) {
  asm("v_pk_fma_f32 %0, %1, %2, %0 op_sel:[0,0,0] op_sel_hi:[0,1,1]"
      : "+v"(acc) : "v"(v), "v"(e));
  asm("v_pk_fma_f32 %0, %1, %2, %0 op_sel:[1,1,0] op_sel_hi:[1,0,1] neg_lo:[0,1,0]"
      : "+v"(acc) : "v"(v), "v"(e));
}
__device__ __forceinline__ void pk_fma(f2& acc, f2 a, f2 b) {
  asm("v_pk_fma_f32 %0, %1, %2, %0" : "+v"(acc) : "v"(a), "v"(b));
}

#define RSQ2 0.70710678118654752f

__device__ __forceinline__ void bfly8_fwd(f2 v[8]) {
  f2 a0 = v[0] + v[4], b0 = v[0] - v[4];
  f2 a1 = v[1] + v[5], d1 = v[1] - v[5];
  f2 a2 = v[2] + v[6], d2 = v[2] - v[6];
  f2 a3 = v[3] + v[7], d3 = v[3] - v[7];
  f2 b1 = mkf2(RSQ2 * (d1.x + d1.y), RSQ2 * (d1.y - d1.x));
  f2 b3 = mkf2(RSQ2 * (d3.y - d3.x), -RSQ2 * (d3.x + d3.y));
  f2 u0 = a0 + a2, u1 = a0 - a2, u2 = a1 + a3, u3 = a1 - a3;
  v[0] = u0 + u2;
  v[2] = mkf2(u1.x + u3.y, u1.y - u3.x);
  v[4] = u0 - u2;
  v[6] = mkf2(u1.x - u3.y, u1.y + u3.x);
  f2 w0 = mkf2(b0.x + d2.y, b0.y - d2.x);
  f2 w1 = mkf2(b0.x - d2.y, b0.y + d2.x);
  f2 w2 = b1 + b3, w3 = b1 - b3;
  v[1] = w0 + w2;
  v[3] = mkf2(w1.x + w3.y, w1.y - w3.x);
  v[5] = w0 - w2;
  v[7] = mkf2(w1.x - w3.y, w1.y + w3.x);
}

__device__ __forceinline__ void bfly8_inv(f2 v[8]) {
  f2 a0 = v[0] + v[4], b0 = v[0] - v[4];
  f2 a1 = v[1] + v[5], d1 = v[1] - v[5];
  f2 a2 = v[2] + v[6], d2 = v[2] - v[6];
  f2 a3 = v[3] + v[7], d3 = v[3] - v[7];
  f2 b1 = mkf2(RSQ2 * (d1.x - d1.y), RSQ2 * (d1.x + d1.y));
  f2 b3 = mkf2(-RSQ2 * (d3.x + d3.y), RSQ2 * (d3.x - d3.y));
  f2 u0 = a0 + a2, u1 = a0 - a2, u2 = a1 + a3, u3 = a1 - a3;
  v[0] = u0 + u2;
  v[2] = mkf2(u1.x - u3.y, u1.y + u3.x);
  v[4] = u0 - u2;
  v[6] = mkf2(u1.x + u3.y, u1.y - u3.x);
  f2 w0 = mkf2(b0.x - d2.y, b0.y + d2.x);
  f2 w1 = mkf2(b0.x + d2.y, b0.y - d2.x);
  f2 w2 = b1 + b3, w3 = b1 - b3;
  v[1] = w0 + w2;
  v[3] = mkf2(w1.x - w3.y, w1.y + w3.x);
  v[5] = w0 - w2;
  v[7] = mkf2(w1.x + w3.y, w1.y - w3.x);
}

// twiddle both problem-streams with ONE set of powers (amortized 2x)
__device__ __forceinline__ void twiddle7x2(f2 va[8], f2 vb[8], f2 w1) {
  f2 w2 = cmul_pk(w1, w1), w3 = cmul_pk(w2, w1), w4 = cmul_pk(w2, w2),
     w5 = cmul_pk(w3, w2), w6 = cmul_pk(w3, w3), w7 = cmul_pk(w4, w3);
  va[1] = cmul_pk(va[1], w1); va[2] = cmul_pk(va[2], w2); va[3] = cmul_pk(va[3], w3);
  va[4] = cmul_pk(va[4], w4); va[5] = cmul_pk(va[5], w5); va[6] = cmul_pk(va[6], w6);
  va[7] = cmul_pk(va[7], w7);
  vb[1] = cmul_pk(vb[1], w1); vb[2] = cmul_pk(vb[2], w2); vb[3] = cmul_pk(vb[3], w3);
  vb[4] = cmul_pk(vb[4], w4); vb[5] = cmul_pk(vb[5], w5); vb[6] = cmul_pk(vb[6], w6);
  vb[7] = cmul_pk(vb[7], w7);
}
__device__ __forceinline__ void twiddle7x2c(f2 va[8], f2 vb[8], f2 w1) {
  f2 w2 = cmul_pk(w1, w1), w3 = cmul_pk(w2, w1), w4 = cmul_pk(w2, w2),
     w5 = cmul_pk(w3, w2), w6 = cmul_pk(w3, w3), w7 = cmul_pk(w4, w3);
  va[1] = cmulc_pk(va[1], w1); va[2] = cmulc_pk(va[2], w2); va[3] = cmulc_pk(va[3], w3);
  va[4] = cmulc_pk(va[4], w4); va[5] = cmulc_pk(va[5], w5); va[6] = cmulc_pk(va[6], w6);
  va[7] = cmulc_pk(va[7], w7);
  vb[1] = cmulc_pk(vb[1], w1); vb[2] = cmulc_pk(vb[2], w2); vb[3] = cmulc_pk(vb[3], w3);
  vb[4] = cmulc_pk(vb[4], w4); vb[5] = cmulc_pk(vb[5], w5); vb[6] = cmulc_pk(vb[6], w6);
  vb[7] = cmulc_pk(vb[7], w7);
}

#define WAVE_SYNC() asm volatile("s_waitcnt lgkmcnt(0)" ::: "memory")

// ---------------- param precompute ----------------
__global__ __launch_bounds__(256) void s4_prep(
    const float* __restrict__ Lre, const float* __restrict__ Lim,
    const float* __restrict__ Pre, const float* __restrict__ Pim,
    const float* __restrict__ Bre, const float* __restrict__ Bim,
    const float* __restrict__ Cre, const float* __restrict__ Cim)
{
  int idx = blockIdx.x * 256 + threadIdx.x;
  if (idx >= NH * NSTATE) return;
  float lr = Lre[idx], li = Lim[idx];
  float pr = Pre[idx], pi = Pim[idx];
  float br = Bre[idx], bi = Bim[idx];
  float cr = Cre[idx], ci = Cim[idx];
  g_pA[idx] = make_float4(lr, li, pr * pr + pi * pi, 0.0f);
  g_pB[idx] = make_float4(cr * br + ci * bi, cr * bi - ci * br,
                          cr * pr + ci * pi, cr * pi - ci * pr);
  g_pC[idx] = make_float2(pr * br + pi * bi, pr * bi - pi * br);
}

// ---------------- frequency-domain S4 kernel ----------------
// Grid NH*8 x 256. Thread (h,j), j in [0,2048): points A: l=j and B: conj mirror.
// Params via wave-uniform global loads (scalar path) -> zero DS traffic.
__global__ __launch_bounds__(256) void s4_kernel_freq(const float* __restrict__ log_step)
{
  const int blk = blockIdx.x;
  const int h = blk >> 3;
  const int j = ((blk & 7) << 8) | threadIdx.x;  // 0..2047

  const float step = expf(log_step[h]);
  const float ts = 2.0f / step;
  const float NEG2PI = -6.2831853071795864769f;

  float gar, gai, car, cai, gbr, gbi, cbr, cbi;
  {
    float so, co;
    sincosf(NEG2PI * ((float)j * (1.0f / (float)LEN)), &so, &co);
    float dr = 1.0f + co, di = so;
    float inv = 1.0f / fmaf(dr, dr, di * di);
    car = 2.0f * dr * inv; cai = -2.0f * di * inv;
    float nr = 1.0f - co, ni = -so;
    gar = ts * (fmaf(nr, dr, ni * di) * inv);
    gai = ts * (fmaf(ni, dr, -nr * di) * inv);
  }
  if (j == 0) {
    float so, co;
    sincosf(NEG2PI * 0.5f, &so, &co);
    float dr = 1.0f + co, di = so;
    float inv = 1.0f / fmaf(dr, dr, di * di);
    cbr = 2.0f * dr * inv; cbi = -2.0f * di * inv;
    float nr = 1.0f - co, ni = -so;
    gbr = ts * (fmaf(nr, dr, ni * di) * inv);
    gbi = ts * (fmaf(ni, dr, -nr * di) * inv);
  } else {
    gbr = gar; gbi = -gai; cbr = car; cbi = -cai;
  }
  const f2 gA = mkf2(gar, gai);
  const f2 gB = mkf2(gbr, gbi);

  f2 A00 = {0,0}, A01 = {0,0}, A10 = {0,0}, A11 = {0,0};
  f2 B00 = {0,0}, B01 = {0,0}, B10 = {0,0}, B11 = {0,0};

  const float4* __restrict__ pa = g_pA + h * NSTATE;
  const float4* __restrict__ pb = g_pB + h * NSTATE;
  const float2* __restrict__ pc = g_pC + h * NSTATE;

#pragma unroll 8
  for (int n = 0; n < NSTATE; ++n) {
    float4 L4 = pa[n];
    float4 V4 = pb[n];
    float2 C2 = pc[n];
    f2 lam = mkf2(L4.x, L4.y);
    f2 pp  = mkf2(L4.z, L4.z);
    f2 v0  = mkf2(V4.x, V4.y);
    f2 v1  = mkf2(V4.z, V4.w);
    f2 v2  = mkf2(C2.x, C2.y);
    {
      f2 d = gA - lam;
      float idn = __builtin_amdgcn_rcpf(fmaf(d.x, d.x, d.y * d.y));
      f2 e = mkf2(d.x * idn, -(d.y * idn));
      cmac_pk(A00, v0, e); cmac_pk(A01, v1, e);
      cmac_pk(A10, v2, e); pk_fma(A11, pp, e);
    }
    {
      f2 d = gB - lam;
      float idn = __builtin_amdgcn_rcpf(fmaf(d.x, d.x, d.y * d.y));
      f2 e = mkf2(d.x * idn, -(d.y * idn));
      cmac_pk(B00, v0, e); cmac_pk(B01, v1, e);
      cmac_pk(B10, v2, e); pk_fma(B11, pp, e);
    }
  }

#define FINISH(cr_, ci_, k00,k01,k10,k11, Kr, Ki)                            \
  {                                                                          \
    float rr = 1.0f + k11.x, ri = k11.y;                                     \
    float rinv = 1.0f / fmaf(rr, rr, ri * ri);                               \
    float pr_ = k01.x * k10.x - k01.y * k10.y;                               \
    float pi_ = k01.x * k10.y + k01.y * k10.x;                               \
    float wr = (pr_ * rr + pi_ * ri) * rinv;                                 \
    float wi = (pi_ * rr - pr_ * ri) * rinv;                                 \
    float sr = k00.x - wr, si = k00.y - wi;                                  \
    Kr = cr_ * sr - ci_ * si; Ki = cr_ * si + ci_ * sr;                      \
  }

  float Kar, Kai, Kbr, Kbi;
  FINISH(car, cai, A00, A01, A10, A11, Kar, Kai)
  FINISH(cbr, cbi, B00, B01, B10, B11, Kbr, Kbi)
#undef FINISH

  f2* out = g_ksym + (size_t)h * LEN;
  if (j == 0) {
    out[rev8_12(0)]    = mkf2(Kar, 0.0f);
    out[rev8_12(2048)] = mkf2(Kbr, 0.0f);
  } else {
    float fr = 0.5f * (Kar + Kbr), fi = 0.5f * (Kai - Kbi);
    out[rev8_12(j)]       = mkf2(fr, fi);
    out[rev8_12(LEN - j)] = mkf2(fr, -fi);
  }
}

// ---------------- FFT convolution: TWO problems per block, float4-packed LDS ----
// Problem A = rows (q, q+8), problem B = rows (q+4, q+12), packed {A.re,A.im,B.re,B.im}
// in one float4 LDS slot -> every LDS op is one ds_*_b128 serving BOTH problems.
// Unpadded 4096-slot layout (exactly 64 KB) made conflict-free by the XOR swizzle
// idx ^= (idx>>3)&7, applied per access pattern below.
__global__ __launch_bounds__(512, 4) void s4_fftconv(const float* __restrict__ u,
                                                    float* __restrict__ y)
{
  __shared__ float4 X[4096];   // 64 KB exactly

  const int t = threadIdx.x;
  const int bid = blockIdx.x;
  const int h  = bid & (NH - 1);
  const int q  = bid >> 8;      // 0..3

  const int w  = t >> 6;
  const int i  = t & 63;
  const int i3 = i >> 3;
  const int i7 = i & 7;

  float c1, s1, c2, s2, c3, s3;
  sincosf((float)t  * (-6.2831853071795864769f / 4096.0f), &s1, &c1);
  sincosf((float)i  * (-6.2831853071795864769f /  512.0f), &s2, &c2);
  sincosf((float)i7 * (-6.2831853071795864769f /   64.0f), &s3, &c3);
  const f2 W1 = mkf2(c1, s1), W2 = mkf2(c2, s2), W3 = mkf2(c3, s3);

  const float* uA1 = u + ((size_t)q        * NH + h) * LEN;
  const float* uA2 = u + ((size_t)(q + 8)  * NH + h) * LEN;
  const float* uB1 = u + ((size_t)(q + 4)  * NH + h) * LEN;
  const float* uB2 = u + ((size_t)(q + 12) * NH + h) * LEN;

  f2 va[8], vb[8];
#pragma unroll
  for (int m = 0; m < 8; ++m) {
    va[m] = mkf2(uA1[t + 512 * m], uA2[t + 512 * m]);
    vb[m] = mkf2(uB1[t + 512 * m], uB2[t + 512 * m]);
  }
  bfly8_fwd(va); bfly8_fwd(vb);
  twiddle7x2(va, vb, W1);
  const int base1 = t ^ ((t >> 3) & 7);       // swz(512m + t) = 512m + (t^r1)
#pragma unroll
  for (int m = 0; m < 8; ++m)
    X[512 * m + base1] = make_float4(va[m].x, va[m].y, vb[m].x, vb[m].y);

  // K fragment: issue before the barrier so HBM latency hides under it.
  const float4* kp = (const float4*)(g_ksym + (size_t)h * LEN + 8 * t);
  float4 k0 = kp[0], k1 = kp[1], k2 = kp[2], k3 = kp[3];
  __syncthreads();                            // block barrier #1

  // ---- stage 2 (stride 64, in-place, wave-local from here) ----
  const int base2 = 512 * w + (i ^ i3);
#pragma unroll
  for (int m = 0; m < 8; ++m) {
    float4 xv = X[base2 + 64 * m];
    va[m] = mkf2(xv.x, xv.y); vb[m] = mkf2(xv.z, xv.w);
  }
  bfly8_fwd(va); bfly8_fwd(vb);
  twiddle7x2(va, vb, W2);
#pragma unroll
  for (int m = 0; m < 8; ++m)
    X[base2 + 64 * m] = make_float4(va[m].x, va[m].y, vb[m].x, vb[m].y);
  WAVE_SYNC();

  // ---- stage 3 (stride 8, in-place) ----
  int a3[8];
  {
    const int b3 = 512 * w + 64 * i3;
#pragma unroll
    for (int m = 0; m < 8; ++m) a3[m] = b3 + 8 * m + (i7 ^ m);
  }
#pragma unroll
  for (int m = 0; m < 8; ++m) {
    float4 xv = X[a3[m]];
    va[m] = mkf2(xv.x, xv.y); vb[m] = mkf2(xv.z, xv.w);
  }
  bfly8_fwd(va); bfly8_fwd(vb);
  twiddle7x2(va, vb, W3);
#pragma unroll
  for (int m = 0; m < 8; ++m)
    X[a3[m]] = make_float4(va[m].x, va[m].y, vb[m].x, vb[m].y);
  WAVE_SYNC();

  // ---- stage 4 fwd + pointwise + stage 4 inv (registers; shared K) ----
  int a4[8];
  {
    const int b4 = 512 * w + 8 * i;
#pragma unroll
    for (int m = 0; m < 8; ++m) a4[m] = b4 + (m ^ i7);
  }
#pragma unroll
  for (int m = 0; m < 8; ++m) {
    float4 xv = X[a4[m]];
    va[m] = mkf2(xv.x, xv.y); vb[m] = mkf2(xv.z, xv.w);
  }
  bfly8_fwd(va); bfly8_fwd(vb);
  {
    f2 kk0 = mkf2(k0.x,k0.y), kk1 = mkf2(k0.z,k0.w), kk2 = mkf2(k1.x,k1.y), kk3 = mkf2(k1.z,k1.w);
    f2 kk4 = mkf2(k2.x,k2.y), kk5 = mkf2(k2.z,k2.w), kk6 = mkf2(k3.x,k3.y), kk7 = mkf2(k3.z,k3.w);
    va[0] = cmul_pk(va[0], kk0); vb[0] = cmul_pk(vb[0], kk0);
    va[1] = cmul_pk(va[1], kk1); vb[1] = cmul_pk(vb[1], kk1);
    va[2] = cmul_pk(va[2], kk2); vb[2] = cmul_pk(vb[2], kk2);
    va[3] = cmul_pk(va[3], kk3); vb[3] = cmul_pk(vb[3], kk3);
    va[4] = cmul_pk(va[4], kk4); vb[4] = cmul_pk(vb[4], kk4);
    va[5] = cmul_pk(va[5], kk5); vb[5] = cmul_pk(vb[5], kk5);
    va[6] = cmul_pk(va[6], kk6); vb[6] = cmul_pk(vb[6], kk6);
    va[7] = cmul_pk(va[7], kk7); vb[7] = cmul_pk(vb[7], kk7);
  }
  bfly8_inv(va); bfly8_inv(vb);
#pragma unroll
  for (int m = 0; m < 8; ++m)
    X[a4[m]] = make_float4(va[m].x, va[m].y, vb[m].x, vb[m].y);
  WAVE_SYNC();

  // ---- stage 3 inverse ----
#pragma unroll
  for (int m = 0; m < 8; ++m) {
    float4 xv = X[a3[m]];
    va[m] = mkf2(xv.x, xv.y); vb[m] = mkf2(xv.z, xv.w);
  }
  twiddle7x2c(va, vb, W3);
  bfly8_inv(va); bfly8_inv(vb);
#pragma unroll
  for (int m = 0; m < 8; ++m)
    X[a3[m]] = make_float4(va[m].x, va[m].y, vb[m].x, vb[m].y);
  WAVE_SYNC();

  // ---- stage 2 inverse ----
#pragma unroll
  for (int m = 0; m < 8; ++m) {
    float4 xv = X[base2 + 64 * m];
    va[m] = mkf2(xv.x, xv.y); vb[m] = mkf2(xv.z, xv.w);
  }
  twiddle7x2c(va, vb, W2);
  bfly8_inv(va); bfly8_inv(vb);
#pragma unroll
  for (int m = 0; m < 8; ++m)
    X[base2 + 64 * m] = make_float4(va[m].x, va[m].y, vb[m].x, vb[m].y);
  __syncthreads();                            // block barrier #2

  // ---- stage 1 inverse (block-wide gather) ----
#pragma unroll
  for (int m = 0; m < 8; ++m) {
    float4 xv = X[512 * m + base1];
    va[m] = mkf2(xv.x, xv.y); vb[m] = mkf2(xv.z, xv.w);
  }
  twiddle7x2c(va, vb, W1);
  bfly8_inv(va); bfly8_inv(vb);

  float* yA1 = y + ((size_t)q        * NH + h) * LEN;
  float* yA2 = y + ((size_t)(q + 8)  * NH + h) * LEN;
  float* yB1 = y + ((size_t)(q + 4)  * NH + h) * LEN;
  float* yB2 = y + ((size_t)(q + 12) * NH + h) * LEN;
  const float sc = 1.0f / (float)LEN;
#pragma unroll
  for (int p = 0; p < 8; ++p) {
    yA1[t + 512 * p] = va[p].x * sc;
    yA2[t + 512 * p] = va[p].y * sc;
    yB1[t + 512 * p] = vb[p].x * sc;
    yB2[t + 512 * p] = vb[p].y * sc;
  }
}

extern "C" void kernel_launch(void* const* d_in, const int* in_sizes, int n_in,
                              void* d_out, int out_size, void* d_ws, size_t ws_size,
                              hipStream_t stream) {
  const float* u    = (const float*)d_in[0];
  const float* Lre  = (const float*)d_in[1];
  const float* Lim  = (const float*)d_in[2];
  const float* Pre  = (const float*)d_in[3];
  const float* Pim  = (const float*)d_in[4];
  const float* Bre  = (const float*)d_in[5];
  const float* Bim  = (const float*)d_in[6];
  const float* Cre  = (const float*)d_in[7];
  const float* Cim  = (const float*)d_in[8];
  const float* lstep = (const float*)d_in[9];
  float* y = (float*)d_out;

  s4_prep<<<(NH * NSTATE + 255) / 256, 256, 0, stream>>>(Lre, Lim, Pre, Pim, Bre, Bim, Cre, Cim);
  s4_kernel_freq<<<NH * 8, 256, 0, stream>>>(lstep);
  s4_fftconv<<<NH * 4, 512, 0, stream>>>(u, y);
}

// Round 5
// 182.660 us; speedup vs baseline: 1.0412x; 1.0412x over previous
//
#include <hip/hip_runtime.h>
#include <math.h>

#define NSTATE 64
#define LEN    4096
#define NH     256
#define NB     16

typedef float f2 __attribute__((ext_vector_type(2)));

// K in base-8 digit-reversed order (fftconv consumption order).
__device__ f2 g_ksym[NH * LEN];
// per-(h,n) Cauchy params: A={lam_r,lam_i,|P|^2,pad} B={v0r,v0i,v1r,v1i} C={v2r,v2i}
// Global (not LDS): read via wave-uniform s_load -> scalar cache, zero DS-pipe cost.
__device__ float4 g_pA[NH * NSTATE];
__device__ float4 g_pB[NH * NSTATE];
__device__ float2 g_pC[NH * NSTATE];

__device__ __forceinline__ int rev8_12(int p) {
  return ((p & 7) << 9) | (((p >> 3) & 7) << 6) | (((p >> 6) & 7) << 3) | (p >> 9);
}

__device__ __forceinline__ f2 mkf2(float a, float b){ f2 r; r.x = a; r.y = b; return r; }

// ---------------- packed-f32 complex primitives (VOP3P) ----------------
__device__ __forceinline__ f2 cmul_pk(f2 a, f2 b) {
  f2 t, r;
  asm("v_pk_mul_f32 %0, %1, %2 op_sel:[0,0] op_sel_hi:[0,1]"
      : "=v"(t) : "v"(a), "v"(b));
  asm("v_pk_fma_f32 %0, %1, %2, %3 op_sel:[1,1,0] op_sel_hi:[1,0,1] neg_lo:[0,1,0]"
      : "=v"(r) : "v"(a), "v"(b), "v"(t));
  return r;
}
__device__ __forceinline__ f2 cmulc_pk(f2 a, f2 b) {
  f2 t, r;
  asm("v_pk_mul_f32 %0, %1, %2 op_sel:[0,0] op_sel_hi:[0,1] neg_hi:[0,1]"
      : "=v"(t) : "v"(a), "v"(b));
  asm("v_pk_fma_f32 %0, %1, %2, %3 op_sel:[1,1,0] op_sel_hi:[1,0,1]"
      : "=v"(r) : "v"(a), "v"(b), "v"(t));
  return r;
}
__device__ __forceinline__ void cmac_pk(f2& acc, f2 v, f2 e) {
  asm("v_pk_fma_f32 %0, %1, %2, %0 op_sel:[0,0,0] op_sel_hi:[0,1,1]"
      : "+v"(acc) : "v"(v), "v"(e));
  asm("v_pk_fma_f32 %0, %1, %2, %0 op_sel:[1,1,0] op_sel_hi:[1,0,1] neg_lo:[0,1,0]"
      : "+v"(acc) : "v"(v), "v"(e));
}
__device__ __forceinline__ void pk_fma(f2& acc, f2 a, f2 b) {
  asm("v_pk_fma_f32 %0, %1, %2, %0" : "+v"(acc) : "v"(a), "v"(b));
}

#define RSQ2 0.70710678118654752f

__device__ __forceinline__ void bfly8_fwd(f2 v[8]) {
  f2 a0 = v[0] + v[4], b0 = v[0] - v[4];
  f2 a1 = v[1] + v[5], d1 = v[1] - v[5];
  f2 a2 = v[2] + v[6], d2 = v[2] - v[6];
  f2 a3 = v[3] + v[7], d3 = v[3] - v[7];
  f2 b1 = mkf2(RSQ2 * (d1.x + d1.y), RSQ2 * (d1.y - d1.x));
  f2 b3 = mkf2(RSQ2 * (d3.y - d3.x), -RSQ2 * (d3.x + d3.y));
  f2 u0 = a0 + a2, u1 = a0 - a2, u2 = a1 + a3, u3 = a1 - a3;
  v[0] = u0 + u2;
  v[2] = mkf2(u1.x + u3.y, u1.y - u3.x);
  v[4] = u0 - u2;
  v[6] = mkf2(u1.x - u3.y, u1.y + u3.x);
  f2 w0 = mkf2(b0.x + d2.y, b0.y - d2.x);
  f2 w1 = mkf2(b0.x - d2.y, b0.y + d2.x);
  f2 w2 = b1 + b3, w3 = b1 - b3;
  v[1] = w0 + w2;
  v[3] = mkf2(w1.x + w3.y, w1.y - w3.x);
  v[5] = w0 - w2;
  v[7] = mkf2(w1.x - w3.y, w1.y + w3.x);
}

__device__ __forceinline__ void bfly8_inv(f2 v[8]) {
  f2 a0 = v[0] + v[4], b0 = v[0] - v[4];
  f2 a1 = v[1] + v[5], d1 = v[1] - v[5];
  f2 a2 = v[2] + v[6], d2 = v[2] - v[6];
  f2 a3 = v[3] + v[7], d3 = v[3] - v[7];
  f2 b1 = mkf2(RSQ2 * (d1.x - d1.y), RSQ2 * (d1.x + d1.y));
  f2 b3 = mkf2(-RSQ2 * (d3.x + d3.y), RSQ2 * (d3.x - d3.y));
  f2 u0 = a0 + a2, u1 = a0 - a2, u2 = a1 + a3, u3 = a1 - a3;
  v[0] = u0 + u2;
  v[2] = mkf2(u1.x - u3.y, u1.y + u3.x);
  v[4] = u0 - u2;
  v[6] = mkf2(u1.x + u3.y, u1.y - u3.x);
  f2 w0 = mkf2(b0.x - d2.y, b0.y + d2.x);
  f2 w1 = mkf2(b0.x + d2.y, b0.y - d2.x);
  f2 w2 = b1 + b3, w3 = b1 - b3;
  v[1] = w0 + w2;
  v[3] = mkf2(w1.x - w3.y, w1.y + w3.x);
  v[5] = w0 - w2;
  v[7] = mkf2(w1.x + w3.y, w1.y - w3.x);
}

// forward twiddle: v[m] *= w1^m
__device__ __forceinline__ void twiddle7(f2 v[8], f2 w1) {
  f2 w2 = cmul_pk(w1, w1);
  f2 w3 = cmul_pk(w2, w1);
  f2 w4 = cmul_pk(w2, w2);
  f2 w5 = cmul_pk(w3, w2);
  f2 w6 = cmul_pk(w3, w3);
  f2 w7 = cmul_pk(w4, w3);
  v[1] = cmul_pk(v[1], w1); v[2] = cmul_pk(v[2], w2); v[3] = cmul_pk(v[3], w3);
  v[4] = cmul_pk(v[4], w4); v[5] = cmul_pk(v[5], w5); v[6] = cmul_pk(v[6], w6);
  v[7] = cmul_pk(v[7], w7);
}
// inverse twiddle: v[m] *= conj(w1^m)
__device__ __forceinline__ void twiddle7c(f2 v[8], f2 w1) {
  f2 w2 = cmul_pk(w1, w1);
  f2 w3 = cmul_pk(w2, w1);
  f2 w4 = cmul_pk(w2, w2);
  f2 w5 = cmul_pk(w3, w2);
  f2 w6 = cmul_pk(w3, w3);
  f2 w7 = cmul_pk(w4, w3);
  v[1] = cmulc_pk(v[1], w1); v[2] = cmulc_pk(v[2], w2); v[3] = cmulc_pk(v[3], w3);
  v[4] = cmulc_pk(v[4], w4); v[5] = cmulc_pk(v[5], w5); v[6] = cmulc_pk(v[6], w6);
  v[7] = cmulc_pk(v[7], w7);
}

#define WAVE_SYNC() asm volatile("s_waitcnt lgkmcnt(0)" ::: "memory")

// ---------------- param precompute ----------------
__global__ __launch_bounds__(256) void s4_prep(
    const float* __restrict__ Lre, const float* __restrict__ Lim,
    const float* __restrict__ Pre, const float* __restrict__ Pim,
    const float* __restrict__ Bre, const float* __restrict__ Bim,
    const float* __restrict__ Cre, const float* __restrict__ Cim)
{
  int idx = blockIdx.x * 256 + threadIdx.x;
  if (idx >= NH * NSTATE) return;
  float lr = Lre[idx], li = Lim[idx];
  float pr = Pre[idx], pi = Pim[idx];
  float br = Bre[idx], bi = Bim[idx];
  float cr = Cre[idx], ci = Cim[idx];
  g_pA[idx] = make_float4(lr, li, pr * pr + pi * pi, 0.0f);
  g_pB[idx] = make_float4(cr * br + ci * bi, cr * bi - ci * br,
                          cr * pr + ci * pi, cr * pi - ci * pr);
  g_pC[idx] = make_float2(pr * br + pi * bi, pr * bi - pi * br);
}

// ---------------- frequency-domain S4 kernel ----------------
// Grid NH*8 x 256. Thread (h,j), j in [0,2048): points A: l=j and B: conj mirror.
// Params via wave-uniform global loads (scalar path) -> zero DS traffic.
__global__ __launch_bounds__(256) void s4_kernel_freq(const float* __restrict__ log_step)
{
  const int blk = blockIdx.x;
  const int h = blk >> 3;
  const int j = ((blk & 7) << 8) | threadIdx.x;  // 0..2047

  const float step = expf(log_step[h]);
  const float ts = 2.0f / step;
  const float NEG2PI = -6.2831853071795864769f;

  float gar, gai, car, cai, gbr, gbi, cbr, cbi;
  {
    float so, co;
    sincosf(NEG2PI * ((float)j * (1.0f / (float)LEN)), &so, &co);
    float dr = 1.0f + co, di = so;
    float inv = 1.0f / fmaf(dr, dr, di * di);
    car = 2.0f * dr * inv; cai = -2.0f * di * inv;
    float nr = 1.0f - co, ni = -so;
    gar = ts * (fmaf(nr, dr, ni * di) * inv);
    gai = ts * (fmaf(ni, dr, -nr * di) * inv);
  }
  if (j == 0) {
    float so, co;
    sincosf(NEG2PI * 0.5f, &so, &co);
    float dr = 1.0f + co, di = so;
    float inv = 1.0f / fmaf(dr, dr, di * di);
    cbr = 2.0f * dr * inv; cbi = -2.0f * di * inv;
    float nr = 1.0f - co, ni = -so;
    gbr = ts * (fmaf(nr, dr, ni * di) * inv);
    gbi = ts * (fmaf(ni, dr, -nr * di) * inv);
  } else {
    gbr = gar; gbi = -gai; cbr = car; cbi = -cai;
  }
  const f2 gA = mkf2(gar, gai);
  const f2 gB = mkf2(gbr, gbi);

  f2 A00 = {0,0}, A01 = {0,0}, A10 = {0,0}, A11 = {0,0};
  f2 B00 = {0,0}, B01 = {0,0}, B10 = {0,0}, B11 = {0,0};

  const float4* __restrict__ pa = g_pA + h * NSTATE;
  const float4* __restrict__ pb = g_pB + h * NSTATE;
  const float2* __restrict__ pc = g_pC + h * NSTATE;

#pragma unroll 8
  for (int n = 0; n < NSTATE; ++n) {
    float4 L4 = pa[n];
    float4 V4 = pb[n];
    float2 C2 = pc[n];
    f2 lam = mkf2(L4.x, L4.y);
    f2 pp  = mkf2(L4.z, L4.z);
    f2 v0  = mkf2(V4.x, V4.y);
    f2 v1  = mkf2(V4.z, V4.w);
    f2 v2  = mkf2(C2.x, C2.y);
    {
      f2 d = gA - lam;
      float idn = __builtin_amdgcn_rcpf(fmaf(d.x, d.x, d.y * d.y));
      f2 e = mkf2(d.x * idn, -(d.y * idn));
      cmac_pk(A00, v0, e); cmac_pk(A01, v1, e);
      cmac_pk(A10, v2, e); pk_fma(A11, pp, e);
    }
    {
      f2 d = gB - lam;
      float idn = __builtin_amdgcn_rcpf(fmaf(d.x, d.x, d.y * d.y));
      f2 e = mkf2(d.x * idn, -(d.y * idn));
      cmac_pk(B00, v0, e); cmac_pk(B01, v1, e);
      cmac_pk(B10, v2, e); pk_fma(B11, pp, e);
    }
  }

#define FINISH(cr_, ci_, k00,k01,k10,k11, Kr, Ki)                            \
  {                                                                          \
    float rr = 1.0f + k11.x, ri = k11.y;                                     \
    float rinv = 1.0f / fmaf(rr, rr, ri * ri);                               \
    float pr_ = k01.x * k10.x - k01.y * k10.y;                               \
    float pi_ = k01.x * k10.y + k01.y * k10.x;                               \
    float wr = (pr_ * rr + pi_ * ri) * rinv;                                 \
    float wi = (pi_ * rr - pr_ * ri) * rinv;                                 \
    float sr = k00.x - wr, si = k00.y - wi;                                  \
    Kr = cr_ * sr - ci_ * si; Ki = cr_ * si + ci_ * sr;                      \
  }

  float Kar, Kai, Kbr, Kbi;
  FINISH(car, cai, A00, A01, A10, A11, Kar, Kai)
  FINISH(cbr, cbi, B00, B01, B10, B11, Kbr, Kbi)
#undef FINISH

  f2* out = g_ksym + (size_t)h * LEN;
  if (j == 0) {
    out[rev8_12(0)]    = mkf2(Kar, 0.0f);
    out[rev8_12(2048)] = mkf2(Kbr, 0.0f);
  } else {
    float fr = 0.5f * (Kar + Kbr), fi = 0.5f * (Kai - Kbi);
    out[rev8_12(j)]       = mkf2(fr, fi);
    out[rev8_12(LEN - j)] = mkf2(fr, -fi);
  }
}

// ---------------- FFT convolution: register radix-8, 4096 = 8^4 ----------------
// R3 structure (best measured): one problem-pair per block packed in f2
// (.x = row bp, .y = row bp+8), 36 KB LDS (8 waves x 576-slot padded regions,
// 4 blocks/CU), wave-local interior fences, 2 block barriers.
// This round's delta: K-fragment load issued BEFORE barrier #1 so its HBM/L2
// latency hides under stages 1-3 instead of stalling the mid-stage.
__global__ __launch_bounds__(512) void s4_fftconv(const float* __restrict__ u,
                                                 float* __restrict__ y)
{
  __shared__ f2 X[4608];   // 8 waves x 576

  const int t = threadIdx.x;
  const int bid = blockIdx.x;
  const int h  = bid & (NH - 1);
  const int bp = bid >> 8;

  const int w  = t >> 6;        // wave id == radix-8 stage-1 output digit
  const int i  = t & 63;        // lane within wave
  const int i3 = i >> 3;
  const int i7 = i & 7;
  const int R  = 576 * w;       // private LDS region base

  float c1, s1, c2, s2, c3, s3;
  sincosf((float)t  * (-6.2831853071795864769f / 4096.0f), &s1, &c1);
  sincosf((float)i  * (-6.2831853071795864769f /  512.0f), &s2, &c2);
  sincosf((float)i7 * (-6.2831853071795864769f /   64.0f), &s3, &c3);
  const f2 W1 = mkf2(c1, s1), W2 = mkf2(c2, s2), W3 = mkf2(c3, s3);

  const float* u1 = u + ((size_t)bp * NH + h) * LEN;
  const float* u2 = u + ((size_t)(bp + 8) * NH + h) * LEN;

  f2 v[8];
#pragma unroll
  for (int m = 0; m < 8; ++m)
    v[m] = mkf2(u1[t + 512 * m], u2[t + 512 * m]);
  bfly8_fwd(v);
  twiddle7(v, W1);
#pragma unroll
  for (int m = 0; m < 8; ++m) X[576 * m + t] = v[m];   // scatter: group m region

  // K fragment: issue before the barrier; consumed only in the mid-stage,
  // so stages 2-3 cover the load latency.
  const float4* kp = (const float4*)(g_ksym + (size_t)h * LEN + 8 * t);
  float4 k0 = kp[0], k1 = kp[1], k2 = kp[2], k3 = kp[3];

  __syncthreads();                                     // block barrier #1

  // ---- stage 2 (stride 64 within group), wave-local from here ----
#pragma unroll
  for (int m = 0; m < 8; ++m) v[m] = X[R + i + 64 * m];
  bfly8_fwd(v);
  twiddle7(v, W2);
#pragma unroll
  for (int m = 0; m < 8; ++m) X[R + 68 * m + i] = v[m];
  WAVE_SYNC();

  // ---- stage 3 (stride 8) ----
#pragma unroll
  for (int m = 0; m < 8; ++m) v[m] = X[R + 68 * i3 + i7 + 8 * m];
  bfly8_fwd(v);
  twiddle7(v, W3);
#pragma unroll
  for (int m = 0; m < 8; ++m) X[R + 9 * (8 * i3 + m) + i7] = v[m];
  WAVE_SYNC();

  // ---- stage 4 fwd + pointwise + stage 4 inv (registers) ----
  {
#pragma unroll
    for (int m = 0; m < 8; ++m) v[m] = X[R + 9 * i + m];
    bfly8_fwd(v);
    v[0] = cmul_pk(v[0], mkf2(k0.x, k0.y));
    v[1] = cmul_pk(v[1], mkf2(k0.z, k0.w));
    v[2] = cmul_pk(v[2], mkf2(k1.x, k1.y));
    v[3] = cmul_pk(v[3], mkf2(k1.z, k1.w));
    v[4] = cmul_pk(v[4], mkf2(k2.x, k2.y));
    v[5] = cmul_pk(v[5], mkf2(k2.z, k2.w));
    v[6] = cmul_pk(v[6], mkf2(k3.x, k3.y));
    v[7] = cmul_pk(v[7], mkf2(k3.z, k3.w));
    bfly8_inv(v);
#pragma unroll
    for (int p = 0; p < 8; ++p) X[R + 9 * i + p] = v[p];
  }
  WAVE_SYNC();

  // ---- stage 3 inverse ----
#pragma unroll
  for (int m = 0; m < 8; ++m) v[m] = X[R + 9 * (8 * i3 + m) + i7];
  twiddle7c(v, W3);
  bfly8_inv(v);
#pragma unroll
  for (int p = 0; p < 8; ++p) X[R + 68 * i3 + i7 + 8 * p] = v[p];
  WAVE_SYNC();

  // ---- stage 2 inverse ----
#pragma unroll
  for (int m = 0; m < 8; ++m) v[m] = X[R + 68 * m + i];
  twiddle7c(v, W2);
  bfly8_inv(v);
#pragma unroll
  for (int p = 0; p < 8; ++p) X[R + i + 64 * p] = v[p];
  __syncthreads();                                     // block barrier #2

  // ---- stage 1 inverse (block-wide gather) ----
#pragma unroll
  for (int m = 0; m < 8; ++m) v[m] = X[576 * m + t];
  twiddle7c(v, W1);
  bfly8_inv(v);

  float* y1 = y + ((size_t)bp * NH + h) * LEN;
  float* y2 = y + ((size_t)(bp + 8) * NH + h) * LEN;
  const float sc = 1.0f / (float)LEN;
#pragma unroll
  for (int p = 0; p < 8; ++p) {
    y1[t + 512 * p] = v[p].x * sc;
    y2[t + 512 * p] = v[p].y * sc;
  }
}

extern "C" void kernel_launch(void* const* d_in, const int* in_sizes, int n_in,
                              void* d_out, int out_size, void* d_ws, size_t ws_size,
                              hipStream_t stream) {
  const float* u    = (const float*)d_in[0];
  const float* Lre  = (const float*)d_in[1];
  const float* Lim  = (const float*)d_in[2];
  const float* Pre  = (const float*)d_in[3];
  const float* Pim  = (const float*)d_in[4];
  const float* Bre  = (const float*)d_in[5];
  const float* Bim  = (const float*)d_in[6];
  const float* Cre  = (const float*)d_in[7];
  const float* Cim  = (const float*)d_in[8];
  const float* lstep = (const float*)d_in[9];
  float* y = (float*)d_out;

  s4_prep<<<(NH * NSTATE + 255) / 256, 256, 0, stream>>>(Lre, Lim, Pre, Pim, Bre, Bim, Cre, Cim);
  s4_kernel_freq<<<NH * 8, 256, 0, stream>>>(lstep);
  s4_fftconv<<<NH * (NB / 2), 512, 0, stream>>>(u, y);
}

// Round 6
// 171.934 us; speedup vs baseline: 1.1062x; 1.0624x over previous
//
#include <hip/hip_runtime.h>
#include <math.h>

#define NSTATE 64
#define LEN    4096
#define NH     256
#define NB     16

typedef float f2 __attribute__((ext_vector_type(2)));

// K in base-8 digit-reversed order (fftconv consumption order).
// Position p holds natural frequency rev8_12(p) (rev8_12 is an involution).
__device__ f2 g_ksym[NH * LEN];

__device__ __forceinline__ int rev8_12(int p) {
  return ((p & 7) << 9) | (((p >> 3) & 7) << 6) | (((p >> 6) & 7) << 3) | (p >> 9);
}

__device__ __forceinline__ f2 mkf2(float a, float b){ f2 r; r.x = a; r.y = b; return r; }

// ---------------- packed-f32 complex primitives (VOP3P) ----------------
__device__ __forceinline__ f2 cmul_pk(f2 a, f2 b) {
  f2 t, r;
  asm("v_pk_mul_f32 %0, %1, %2 op_sel:[0,0] op_sel_hi:[0,1]"
      : "=v"(t) : "v"(a), "v"(b));
  asm("v_pk_fma_f32 %0, %1, %2, %3 op_sel:[1,1,0] op_sel_hi:[1,0,1] neg_lo:[0,1,0]"
      : "=v"(r) : "v"(a), "v"(b), "v"(t));
  return r;
}
__device__ __forceinline__ f2 cmulc_pk(f2 a, f2 b) {
  f2 t, r;
  asm("v_pk_mul_f32 %0, %1, %2 op_sel:[0,0] op_sel_hi:[0,1] neg_hi:[0,1]"
      : "=v"(t) : "v"(a), "v"(b));
  asm("v_pk_fma_f32 %0, %1, %2, %3 op_sel:[1,1,0] op_sel_hi:[1,0,1]"
      : "=v"(r) : "v"(a), "v"(b), "v"(t));
  return r;
}
__device__ __forceinline__ void cmac_pk(f2& acc, f2 v, f2 e) {
  asm("v_pk_fma_f32 %0, %1, %2, %0 op_sel:[0,0,0] op_sel_hi:[0,1,1]"
      : "+v"(acc) : "v"(v), "v"(e));
  asm("v_pk_fma_f32 %0, %1, %2, %0 op_sel:[1,1,0] op_sel_hi:[1,0,1] neg_lo:[0,1,0]"
      : "+v"(acc) : "v"(v), "v"(e));
}
__device__ __forceinline__ void pk_fma(f2& acc, f2 a, f2 b) {
  asm("v_pk_fma_f32 %0, %1, %2, %0" : "+v"(acc) : "v"(a), "v"(b));
}

#define RSQ2 0.70710678118654752f

__device__ __forceinline__ void bfly8_fwd(f2 v[8]) {
  f2 a0 = v[0] + v[4], b0 = v[0] - v[4];
  f2 a1 = v[1] + v[5], d1 = v[1] - v[5];
  f2 a2 = v[2] + v[6], d2 = v[2] - v[6];
  f2 a3 = v[3] + v[7], d3 = v[3] - v[7];
  f2 b1 = mkf2(RSQ2 * (d1.x + d1.y), RSQ2 * (d1.y - d1.x));
  f2 b3 = mkf2(RSQ2 * (d3.y - d3.x), -RSQ2 * (d3.x + d3.y));
  f2 u0 = a0 + a2, u1 = a0 - a2, u2 = a1 + a3, u3 = a1 - a3;
  v[0] = u0 + u2;
  v[2] = mkf2(u1.x + u3.y, u1.y - u3.x);
  v[4] = u0 - u2;
  v[6] = mkf2(u1.x - u3.y, u1.y + u3.x);
  f2 w0 = mkf2(b0.x + d2.y, b0.y - d2.x);
  f2 w1 = mkf2(b0.x - d2.y, b0.y + d2.x);
  f2 w2 = b1 + b3, w3 = b1 - b3;
  v[1] = w0 + w2;
  v[3] = mkf2(w1.x + w3.y, w1.y - w3.x);
  v[5] = w0 - w2;
  v[7] = mkf2(w1.x - w3.y, w1.y + w3.x);
}

__device__ __forceinline__ void bfly8_inv(f2 v[8]) {
  f2 a0 = v[0] + v[4], b0 = v[0] - v[4];
  f2 a1 = v[1] + v[5], d1 = v[1] - v[5];
  f2 a2 = v[2] + v[6], d2 = v[2] - v[6];
  f2 a3 = v[3] + v[7], d3 = v[3] - v[7];
  f2 b1 = mkf2(RSQ2 * (d1.x - d1.y), RSQ2 * (d1.x + d1.y));
  f2 b3 = mkf2(-RSQ2 * (d3.x + d3.y), RSQ2 * (d3.x - d3.y));
  f2 u0 = a0 + a2, u1 = a0 - a2, u2 = a1 + a3, u3 = a1 - a3;
  v[0] = u0 + u2;
  v[2] = mkf2(u1.x - u3.y, u1.y + u3.x);
  v[4] = u0 - u2;
  v[6] = mkf2(u1.x + u3.y, u1.y - u3.x);
  f2 w0 = mkf2(b0.x - d2.y, b0.y + d2.x);
  f2 w1 = mkf2(b0.x + d2.y, b0.y - d2.x);
  f2 w2 = b1 + b3, w3 = b1 - b3;
  v[1] = w0 + w2;
  v[3] = mkf2(w1.x - w3.y, w1.y + w3.x);
  v[5] = w0 - w2;
  v[7] = mkf2(w1.x + w3.y, w1.y - w3.x);
}

// forward twiddle: v[m] *= w1^m
__device__ __forceinline__ void twiddle7(f2 v[8], f2 w1) {
  f2 w2 = cmul_pk(w1, w1);
  f2 w3 = cmul_pk(w2, w1);
  f2 w4 = cmul_pk(w2, w2);
  f2 w5 = cmul_pk(w3, w2);
  f2 w6 = cmul_pk(w3, w3);
  f2 w7 = cmul_pk(w4, w3);
  v[1] = cmul_pk(v[1], w1); v[2] = cmul_pk(v[2], w2); v[3] = cmul_pk(v[3], w3);
  v[4] = cmul_pk(v[4], w4); v[5] = cmul_pk(v[5], w5); v[6] = cmul_pk(v[6], w6);
  v[7] = cmul_pk(v[7], w7);
}
// inverse twiddle: v[m] *= conj(w1^m)
__device__ __forceinline__ void twiddle7c(f2 v[8], f2 w1) {
  f2 w2 = cmul_pk(w1, w1);
  f2 w3 = cmul_pk(w2, w1);
  f2 w4 = cmul_pk(w2, w2);
  f2 w5 = cmul_pk(w3, w2);
  f2 w6 = cmul_pk(w3, w3);
  f2 w7 = cmul_pk(w4, w3);
  v[1] = cmulc_pk(v[1], w1); v[2] = cmulc_pk(v[2], w2); v[3] = cmulc_pk(v[3], w3);
  v[4] = cmulc_pk(v[4], w4); v[5] = cmulc_pk(v[5], w5); v[6] = cmulc_pk(v[6], w6);
  v[7] = cmulc_pk(v[7], w7);
}

#define WAVE_SYNC() asm volatile("s_waitcnt lgkmcnt(0)" ::: "memory")

// ---------------- frequency-domain S4 kernel (prep fused, LDS params, 4 pts) ----
// Grid NH*4 x 256. Thread (h,q), q in [0,1024) evaluates K at FOUR points:
//   A: l=q          B: mirror (4096-q)&4095  (q==0 -> l=2048 direct)
//   C: l=1024+q     D: mirror 3072-q         (conj of C's g,c)
// Params staged in LDS by threads 0..63 (prep fused), read as broadcast
// ds_read (deep lgkmcnt pipelining, no SGPR-pressure stalls — R4 lesson).
// One param read per pole serves 4 point-evals (DS/VALU ratio halved vs R3).
__global__ __launch_bounds__(256) void s4_kernel_freq(
    const float* __restrict__ Lre, const float* __restrict__ Lim,
    const float* __restrict__ Pre, const float* __restrict__ Pim,
    const float* __restrict__ Bre, const float* __restrict__ Bim,
    const float* __restrict__ Cre, const float* __restrict__ Cim,
    const float* __restrict__ log_step)
{
  __shared__ float4 sLam[NSTATE];
  __shared__ float4 sV01[NSTATE];
  __shared__ f2     sV2[NSTATE];

  const int blk = blockIdx.x;
  const int h = blk >> 2;
  const int q = ((blk & 3) << 8) | threadIdx.x;  // 0..1023

  if (threadIdx.x < NSTATE) {
    int idx = h * NSTATE + threadIdx.x;
    float lr = Lre[idx], li = Lim[idx];
    float pr = Pre[idx], pi = Pim[idx];
    float br = Bre[idx], bi = Bim[idx];
    float cr = Cre[idx], ci = Cim[idx];
    float pp = pr * pr + pi * pi;
    sLam[threadIdx.x] = make_float4(lr, li, pp, pp);
    sV01[threadIdx.x] = make_float4(cr * br + ci * bi, cr * bi - ci * br,
                                    cr * pr + ci * pi, cr * pi - ci * pr);
    sV2[threadIdx.x] = mkf2(pr * br + pi * bi, pr * bi - pi * br);
  }

  const float step = expf(log_step[h]);
  const float ts = 2.0f / step;
  const float NEG2PI = -6.2831853071795864769f;

  float gar, gai, car, cai, gbr, gbi, cbr, cbi;
  float gcr, gci, ccr, cci, gdr, gdi, cdr, cdi;
  {
    float so, co;
    sincosf(NEG2PI * ((float)q * (1.0f / (float)LEN)), &so, &co);
    float dr = 1.0f + co, di = so;
    float inv = 1.0f / fmaf(dr, dr, di * di);
    car = 2.0f * dr * inv; cai = -2.0f * di * inv;
    float nr = 1.0f - co, ni = -so;
    gar = ts * (fmaf(nr, dr, ni * di) * inv);
    gai = ts * (fmaf(ni, dr, -nr * di) * inv);
  }
  if (q == 0) {           // point B is l = 2048 (self-paired), compute directly
    float so, co;
    sincosf(NEG2PI * 0.5f, &so, &co);
    float dr = 1.0f + co, di = so;
    float inv = 1.0f / fmaf(dr, dr, di * di);
    cbr = 2.0f * dr * inv; cbi = -2.0f * di * inv;
    float nr = 1.0f - co, ni = -so;
    gbr = ts * (fmaf(nr, dr, ni * di) * inv);
    gbi = ts * (fmaf(ni, dr, -nr * di) * inv);
  } else {                // B = mirror of A: Omega -> conj => g,c -> conj
    gbr = gar; gbi = -gai; cbr = car; cbi = -cai;
  }
  {
    float so, co;
    sincosf(NEG2PI * ((float)(q + 1024) * (1.0f / (float)LEN)), &so, &co);
    float dr = 1.0f + co, di = so;
    float inv = 1.0f / fmaf(dr, dr, di * di);
    ccr = 2.0f * dr * inv; cci = -2.0f * di * inv;
    float nr = 1.0f - co, ni = -so;
    gcr = ts * (fmaf(nr, dr, ni * di) * inv);
    gci = ts * (fmaf(ni, dr, -nr * di) * inv);
  }
  gdr = gcr; gdi = -gci; cdr = ccr; cdi = -cci;

  const f2 gA = mkf2(gar, gai), gB = mkf2(gbr, gbi);
  const f2 gC = mkf2(gcr, gci), gD = mkf2(gdr, gdi);

  f2 A00 = {0,0}, A01 = {0,0}, A10 = {0,0}, A11 = {0,0};
  f2 B00 = {0,0}, B01 = {0,0}, B10 = {0,0}, B11 = {0,0};
  f2 C00 = {0,0}, C01 = {0,0}, C10 = {0,0}, C11 = {0,0};
  f2 D00 = {0,0}, D01 = {0,0}, D10 = {0,0}, D11 = {0,0};

  __syncthreads();

#define CAU(g_, k00,k01,k10,k11)                                             \
  {                                                                          \
    f2 d = g_ - lam;                                                         \
    float idn = __builtin_amdgcn_rcpf(fmaf(d.x, d.x, d.y * d.y));            \
    f2 e = mkf2(d.x * idn, -(d.y * idn));                                    \
    cmac_pk(k00, v0, e); cmac_pk(k01, v1, e);                                \
    cmac_pk(k10, v2, e); pk_fma(k11, pp, e);                                 \
  }

#pragma unroll 4
  for (int n = 0; n < NSTATE; ++n) {
    float4 L4 = sLam[n];
    float4 V4 = sV01[n];
    f2 v2 = sV2[n];
    f2 lam = mkf2(L4.x, L4.y);
    f2 pp  = mkf2(L4.z, L4.w);
    f2 v0  = mkf2(V4.x, V4.y);
    f2 v1  = mkf2(V4.z, V4.w);
    CAU(gA, A00, A01, A10, A11)
    CAU(gB, B00, B01, B10, B11)
    CAU(gC, C00, C01, C10, C11)
    CAU(gD, D00, D01, D10, D11)
  }
#undef CAU

#define FINISH(cr_, ci_, k00,k01,k10,k11, Kr, Ki)                            \
  {                                                                          \
    float rr = 1.0f + k11.x, ri = k11.y;                                     \
    float rinv = 1.0f / fmaf(rr, rr, ri * ri);                               \
    float pr_ = k01.x * k10.x - k01.y * k10.y;                               \
    float pi_ = k01.x * k10.y + k01.y * k10.x;                               \
    float wr = (pr_ * rr + pi_ * ri) * rinv;                                 \
    float wi = (pi_ * rr - pr_ * ri) * rinv;                                 \
    float sr = k00.x - wr, si = k00.y - wi;                                  \
    Kr = cr_ * sr - ci_ * si; Ki = cr_ * si + ci_ * sr;                      \
  }

  float Kar, Kai, Kbr, Kbi, Kcr, Kci, Kdr, Kdi;
  FINISH(car, cai, A00, A01, A10, A11, Kar, Kai)
  FINISH(cbr, cbi, B00, B01, B10, B11, Kbr, Kbi)
  FINISH(ccr, cci, C00, C01, C10, C11, Kcr, Kci)
  FINISH(cdr, cdi, D00, D01, D10, D11, Kdr, Kdi)
#undef FINISH

  f2* out = g_ksym + (size_t)h * LEN;
  if (q == 0) {
    out[rev8_12(0)]    = mkf2(Kar, 0.0f);   // Ksym[0]    = Re K[0]
    out[rev8_12(2048)] = mkf2(Kbr, 0.0f);   // Ksym[2048] = Re K[2048]
  } else {
    float fr = 0.5f * (Kar + Kbr), fi = 0.5f * (Kai - Kbi);
    out[rev8_12(q)]        = mkf2(fr, fi);
    out[rev8_12(LEN - q)]  = mkf2(fr, -fi);  // conj pair
  }
  {
    float fr = 0.5f * (Kcr + Kdr), fi = 0.5f * (Kci - Kdi);
    out[rev8_12(1024 + q)] = mkf2(fr, fi);
    out[rev8_12(3072 - q)] = mkf2(fr, -fi);
  }
}

// ---------------- FFT convolution: register radix-8, 4096 = 8^4 ----------------
// R3 structure (best measured): one problem-pair per block packed in f2
// (.x = row bp, .y = row bp+8), 36 KB LDS (8 waves x 576-slot padded regions,
// 4 blocks/CU), wave-local interior fences, 2 block barriers.
// K-fragment load issued BEFORE barrier #1 so its HBM/L2 latency overlaps stage 1.
__global__ __launch_bounds__(512) void s4_fftconv(const float* __restrict__ u,
                                                 float* __restrict__ y)
{
  __shared__ f2 X[4608];   // 8 waves x 576

  const int t = threadIdx.x;
  const int bid = blockIdx.x;
  const int h  = bid & (NH - 1);
  const int bp = bid >> 8;

  const int w  = t >> 6;        // wave id == radix-8 stage-1 output digit
  const int i  = t & 63;        // lane within wave
  const int i3 = i >> 3;
  const int i7 = i & 7;
  const int R  = 576 * w;       // private LDS region base

  float c1, s1, c2, s2, c3, s3;
  sincosf((float)t  * (-6.2831853071795864769f / 4096.0f), &s1, &c1);
  sincosf((float)i  * (-6.2831853071795864769f /  512.0f), &s2, &c2);
  sincosf((float)i7 * (-6.2831853071795864769f /   64.0f), &s3, &c3);
  const f2 W1 = mkf2(c1, s1), W2 = mkf2(c2, s2), W3 = mkf2(c3, s3);

  const float* u1 = u + ((size_t)bp * NH + h) * LEN;
  const float* u2 = u + ((size_t)(bp + 8) * NH + h) * LEN;

  f2 v[8];
#pragma unroll
  for (int m = 0; m < 8; ++m)
    v[m] = mkf2(u1[t + 512 * m], u2[t + 512 * m]);
  bfly8_fwd(v);
  twiddle7(v, W1);
#pragma unroll
  for (int m = 0; m < 8; ++m) X[576 * m + t] = v[m];   // scatter: group m region

  // K fragment: issue before the barrier; consumed only in the mid-stage.
  const float4* kp = (const float4*)(g_ksym + (size_t)h * LEN + 8 * t);
  float4 k0 = kp[0], k1 = kp[1], k2 = kp[2], k3 = kp[3];

  __syncthreads();                                     // block barrier #1

  // ---- stage 2 (stride 64 within group), wave-local from here ----
#pragma unroll
  for (int m = 0; m < 8; ++m) v[m] = X[R + i + 64 * m];
  bfly8_fwd(v);
  twiddle7(v, W2);
#pragma unroll
  for (int m = 0; m < 8; ++m) X[R + 68 * m + i] = v[m];
  WAVE_SYNC();

  // ---- stage 3 (stride 8) ----
#pragma unroll
  for (int m = 0; m < 8; ++m) v[m] = X[R + 68 * i3 + i7 + 8 * m];
  bfly8_fwd(v);
  twiddle7(v, W3);
#pragma unroll
  for (int m = 0; m < 8; ++m) X[R + 9 * (8 * i3 + m) + i7] = v[m];
  WAVE_SYNC();

  // ---- stage 4 fwd + pointwise + stage 4 inv (registers) ----
  {
#pragma unroll
    for (int m = 0; m < 8; ++m) v[m] = X[R + 9 * i + m];
    bfly8_fwd(v);
    v[0] = cmul_pk(v[0], mkf2(k0.x, k0.y));
    v[1] = cmul_pk(v[1], mkf2(k0.z, k0.w));
    v[2] = cmul_pk(v[2], mkf2(k1.x, k1.y));
    v[3] = cmul_pk(v[3], mkf2(k1.z, k1.w));
    v[4] = cmul_pk(v[4], mkf2(k2.x, k2.y));
    v[5] = cmul_pk(v[5], mkf2(k2.z, k2.w));
    v[6] = cmul_pk(v[6], mkf2(k3.x, k3.y));
    v[7] = cmul_pk(v[7], mkf2(k3.z, k3.w));
    bfly8_inv(v);
#pragma unroll
    for (int p = 0; p < 8; ++p) X[R + 9 * i + p] = v[p];
  }
  WAVE_SYNC();

  // ---- stage 3 inverse ----
#pragma unroll
  for (int m = 0; m < 8; ++m) v[m] = X[R + 9 * (8 * i3 + m) + i7];
  twiddle7c(v, W3);
  bfly8_inv(v);
#pragma unroll
  for (int p = 0; p < 8; ++p) X[R + 68 * i3 + i7 + 8 * p] = v[p];
  WAVE_SYNC();

  // ---- stage 2 inverse ----
#pragma unroll
  for (int m = 0; m < 8; ++m) v[m] = X[R + 68 * m + i];
  twiddle7c(v, W2);
  bfly8_inv(v);
#pragma unroll
  for (int p = 0; p < 8; ++p) X[R + i + 64 * p] = v[p];
  __syncthreads();                                     // block barrier #2

  // ---- stage 1 inverse (block-wide gather) ----
#pragma unroll
  for (int m = 0; m < 8; ++m) v[m] = X[576 * m + t];
  twiddle7c(v, W1);
  bfly8_inv(v);

  float* y1 = y + ((size_t)bp * NH + h) * LEN;
  float* y2 = y + ((size_t)(bp + 8) * NH + h) * LEN;
  const float sc = 1.0f / (float)LEN;
#pragma unroll
  for (int p = 0; p < 8; ++p) {
    y1[t + 512 * p] = v[p].x * sc;
    y2[t + 512 * p] = v[p].y * sc;
  }
}

extern "C" void kernel_launch(void* const* d_in, const int* in_sizes, int n_in,
                              void* d_out, int out_size, void* d_ws, size_t ws_size,
                              hipStream_t stream) {
  const float* u    = (const float*)d_in[0];
  const float* Lre  = (const float*)d_in[1];
  const float* Lim  = (const float*)d_in[2];
  const float* Pre  = (const float*)d_in[3];
  const float* Pim  = (const float*)d_in[4];
  const float* Bre  = (const float*)d_in[5];
  const float* Bim  = (const float*)d_in[6];
  const float* Cre  = (const float*)d_in[7];
  const float* Cim  = (const float*)d_in[8];
  const float* lstep = (const float*)d_in[9];
  float* y = (float*)d_out;

  s4_kernel_freq<<<NH * 4, 256, 0, stream>>>(Lre, Lim, Pre, Pim, Bre, Bim, Cre, Cim, lstep);
  s4_fftconv<<<NH * (NB / 2), 512, 0, stream>>>(u, y);
}